// Round 1
// baseline (377.628 us; speedup 1.0000x reference)
//
#include <hip/hip_runtime.h>
#include <hip/hip_bf16.h>

#define NODE_DIM 256
#define COND_DIM 512
#define OUT_DIM  128
#define HID      64
#define LN_EPS   1e-5f

typedef __attribute__((ext_vector_type(8))) short bf16x8;
typedef __attribute__((ext_vector_type(4))) float f32x4;

__device__ __forceinline__ short f2bf(float f) {
    __hip_bfloat16 h = __float2bfloat16(f);
    return *reinterpret_cast<short*>(&h);
}
__device__ __forceinline__ float bf_lo(unsigned int v) {
    union { unsigned int u; float f; } x; x.u = v << 16; return x.f;
}
__device__ __forceinline__ float bf_hi(unsigned int v) {
    union { unsigned int u; float f; } x; x.u = v & 0xffff0000u; return x.f;
}

// ---------------------------------------------------------------------------
// prep (grid 130 + zero-blocks):
//  blocks 0..127 : cond projection output o (weight-normed) -> gamma/beta
//  block 128     : weight-norm lin_w_v rows -> wlin_bf [128 o][64 k] bf16
//  block 129     : film_w -> fw_bf [64 h][256 k] bf16
//  blocks 130+   : zero deg[] (replaces hipMemsetAsync launch)
// ---------------------------------------------------------------------------
__global__ __launch_bounds__(256) void prep(
    const float* __restrict__ cond_feats,
    const float* __restrict__ cond_w_v,
    const float* __restrict__ cond_w_g,
    const float* __restrict__ cond_b,
    const float* __restrict__ lin_w_v,
    const float* __restrict__ lin_w_g,
    const float* __restrict__ film_w,
    float* __restrict__ gamma, float* __restrict__ beta,
    short* __restrict__ wlin_bf, short* __restrict__ fw_bf,
    int* __restrict__ deg, int N, int B)
{
    const int t = threadIdx.x;
    const int bid = blockIdx.x;
    if (bid >= 130) {
        const int z = bid - 130;
        const int i0 = z * 1024 + t * 4;
        #pragma unroll
        for (int j = 0; j < 4; ++j)
            if (i0 + j < N) deg[i0 + j] = 0;
        return;
    }
    if (bid == 128) {
        if (t < OUT_DIM) {
            const int o = t;
            float nrm = 0.f;
            float w[HID];
            #pragma unroll
            for (int k = 0; k < HID; ++k) {
                w[k] = lin_w_v[o * HID + k];
                nrm += w[k] * w[k];
            }
            const float s = lin_w_g[o] * rsqrtf(nrm);
            #pragma unroll
            for (int k = 0; k < HID; ++k) wlin_bf[o * HID + k] = f2bf(w[k] * s);
        }
        return;
    }
    if (bid == 129) {
        for (int idx = t; idx < HID * NODE_DIM; idx += 256)
            fw_bf[idx] = f2bf(film_w[idx]);
        return;
    }
    const int o = bid;
    const int lane = t & 63;
    const int wv = t >> 6;
    __shared__ float s_cp[64];
    __shared__ float s_nrm;
    float wreg[COND_DIM / 64];
    #pragma unroll
    for (int j = 0; j < COND_DIM / 64; ++j)
        wreg[j] = cond_w_v[o * COND_DIM + j * 64 + lane];
    float nr = 0.f;
    #pragma unroll
    for (int j = 0; j < COND_DIM / 64; ++j) nr += wreg[j] * wreg[j];
    #pragma unroll
    for (int off = 32; off > 0; off >>= 1) nr += __shfl_xor(nr, off, 64);
    if (t == 0) s_nrm = nr;
    for (int b = wv; b < 64; b += 4) {
        float a = 0.f;
        #pragma unroll
        for (int j = 0; j < COND_DIM / 64; ++j)
            a += wreg[j] * cond_feats[b * COND_DIM + j * 64 + lane];
        #pragma unroll
        for (int off = 32; off > 0; off >>= 1) a += __shfl_xor(a, off, 64);
        if (lane == 0) s_cp[b] = a;
    }
    __syncthreads();
    if (t < 64) {
        const float scale = cond_w_g[o] * rsqrtf(s_nrm);
        const float cp = scale * s_cp[t] + cond_b[o];
        if (o < HID) gamma[t * HID + o] = cp + 1.0f;
        else         beta[t * HID + (o - HID)] = cp;
    }
}

// ---------------------------------------------------------------------------
// fused_phase1: deg_count (atomic histogram + epos) interleaved with the
// node FiLM path (GEMM1 + LN + FiLM + relu -> h bf16 [N][64]).
// Pattern d,f (1:1): deg blocks now 1024 edges / 4 per thread — a SINGLE
// round of 4 in-flight returning atomics per thread (was 2 dependent
// rounds), and 2x as many deg blocks resident, to hide the memory-side
// atomic latency that was the kernel's straggler.
// ---------------------------------------------------------------------------
__global__ __launch_bounds__(256) void fused_phase1(
    const float* __restrict__ nf,
    const short* __restrict__ fw_bf,      // [64 h][256 k]
    const float* __restrict__ film_b,
    const float* __restrict__ gamma, const float* __restrict__ beta,
    const int*  __restrict__ n2g,
    unsigned short* __restrict__ h_out,   // [N][64] bf16
    const int* __restrict__ ei,
    int* __restrict__ deg, int* __restrict__ epos,
    int N, int E, int G_film, int G_deg)
{
    const int bid = blockIdx.x;
    const int grp = bid >> 1;
    const int rem = bid & 1;
    const int t = threadIdx.x;

    if (rem == 0) {
        // ---------------- deg_count block: 1024 edges, 4 per thread ----------
        const int deg_id = grp;
        if (deg_id >= G_deg) return;
        const int e0 = deg_id * 1024 + t * 4;
        if (e0 + 3 < E) {
            const int4 d4 = *(const int4*)(ei + E + e0);
            int4 p4;
            p4.x = atomicAdd(&deg[d4.x], 1);
            p4.y = atomicAdd(&deg[d4.y], 1);
            p4.z = atomicAdd(&deg[d4.z], 1);
            p4.w = atomicAdd(&deg[d4.w], 1);
            *(int4*)(epos + e0) = p4;
        } else {
            for (int j = 0; j < 4; ++j) {
                const int e = e0 + j;
                if (e < E) epos[e] = atomicAdd(&deg[ei[E + e]], 1);
            }
        }
        return;
    }

    // ---------------- node film block --------------------------------------
    const int film_id = grp;
    if (film_id >= G_film) return;
    const int w = t >> 6;
    const int lane = t & 63;
    const int c = lane & 15;
    const int quad = lane >> 4;
    const int n0 = film_id * 64;

    f32x4 c1[4];
    #pragma unroll
    for (int q = 0; q < 4; ++q) { c1[q][0]=0.f; c1[q][1]=0.f; c1[q][2]=0.f; c1[q][3]=0.f; }

    const int mnode = n0 + w * 16 + c;
    const int arow = (mnode < N) ? mnode : (N - 1);
    const float* aptr = nf + (size_t)arow * NODE_DIM + quad * 8;

    #pragma unroll 4
    for (int k0 = 0; k0 < NODE_DIM; k0 += 32) {
        const float4 a01 = *(const float4*)(aptr + k0);
        const float4 a23 = *(const float4*)(aptr + k0 + 4);
        bf16x8 af;
        af[0]=f2bf(a01.x); af[1]=f2bf(a01.y); af[2]=f2bf(a01.z); af[3]=f2bf(a01.w);
        af[4]=f2bf(a23.x); af[5]=f2bf(a23.y); af[6]=f2bf(a23.z); af[7]=f2bf(a23.w);
        #pragma unroll
        for (int nt = 0; nt < 4; ++nt) {
            const bf16x8 bfr = *(const bf16x8*)(fw_bf + ((nt * 16 + c) * NODE_DIM + k0 + quad * 8));
            c1[nt] = __builtin_amdgcn_mfma_f32_16x16x32_bf16(af, bfr, c1[nt], 0, 0, 0);
        }
    }

    #pragma unroll
    for (int nt = 0; nt < 4; ++nt) {
        const float b = film_b[nt * 16 + c];
        c1[nt][0] += b; c1[nt][1] += b; c1[nt][2] += b; c1[nt][3] += b;
    }

    // LN per row (node): row = quad*4 + r, cols spread over 16 lanes x 4 tiles
    float sum[4], sq[4];
    #pragma unroll
    for (int r = 0; r < 4; ++r) {
        sum[r] = c1[0][r] + c1[1][r] + c1[2][r] + c1[3][r];
        sq[r]  = c1[0][r]*c1[0][r] + c1[1][r]*c1[1][r]
               + c1[2][r]*c1[2][r] + c1[3][r]*c1[3][r];
    }
    #pragma unroll
    for (int off = 1; off < 16; off <<= 1) {
        #pragma unroll
        for (int r = 0; r < 4; ++r) {
            sum[r] += __shfl_xor(sum[r], off, 64);
            sq[r]  += __shfl_xor(sq[r],  off, 64);
        }
    }
    float mu[4], inv[4];
    int gid[4];
    #pragma unroll
    for (int r = 0; r < 4; ++r) {
        mu[r] = sum[r] * (1.0f / HID);
        float var = sq[r] * (1.0f / HID) - mu[r] * mu[r];
        var = fmaxf(var, 0.f);
        inv[r] = rsqrtf(var + LN_EPS);
        const int nn = n0 + w * 16 + quad * 4 + r;
        gid[r] = n2g[(nn < N) ? nn : (N - 1)];
    }

    #pragma unroll
    for (int r = 0; r < 4; ++r) {
        const int nn = n0 + w * 16 + quad * 4 + r;
        if (nn >= N) continue;
        #pragma unroll
        for (int nt = 0; nt < 4; ++nt) {
            const int col = nt * 16 + c;
            const float ga = gamma[gid[r] * HID + col];
            const float be = beta[gid[r] * HID + col];
            const float v = fmaxf(ga * ((c1[nt][r] - mu[r]) * inv[r]) + be, 0.f);
            h_out[(size_t)nn * HID + col] = (unsigned short)f2bf(v);
        }
    }
}

// ---------------------------------------------------------------------------
// scan (3 small kernels)
// ---------------------------------------------------------------------------
__global__ __launch_bounds__(1024) void scan1(
    const int* __restrict__ deg, int* __restrict__ csr_off,
    int* __restrict__ bsums, int N)
{
    __shared__ int s[1024];
    const int t = threadIdx.x;
    const int i = blockIdx.x * 1024 + t;
    s[t] = (i < N) ? deg[i] : 0;
    __syncthreads();
    for (int off = 1; off < 1024; off <<= 1) {
        const int x = s[t];
        const int y = (t >= off) ? s[t - off] : 0;
        __syncthreads();
        s[t] = x + y;
        __syncthreads();
    }
    if (i < N) csr_off[i + 1] = s[t];
    if (t == 1023) bsums[blockIdx.x] = s[1023];
}

__global__ __launch_bounds__(1024) void scan2(
    const int* __restrict__ bsums, int* __restrict__ boff, int NB)
{
    __shared__ int s[1024];
    const int t = threadIdx.x;
    const int v = (t < NB) ? bsums[t] : 0;
    s[t] = v;
    __syncthreads();
    for (int off = 1; off < 1024; off <<= 1) {
        const int x = s[t];
        const int y = (t >= off) ? s[t - off] : 0;
        __syncthreads();
        s[t] = x + y;
        __syncthreads();
    }
    if (t < NB) boff[t] = s[t] - v;  // exclusive
}

__global__ __launch_bounds__(1024) void scan3(
    int* __restrict__ csr_off, const int* __restrict__ boff, int N)
{
    const int i = blockIdx.x * 1024 + threadIdx.x;
    if (i < N) csr_off[i + 1] += boff[blockIdx.x];
    if (i == 0) csr_off[0] = 0;
}

// ---------------------------------------------------------------------------
// bucket_fill, 4 edges per thread (int4), atomic-free via epos
// ---------------------------------------------------------------------------
__global__ __launch_bounds__(256) void bucket_fill(
    const int* __restrict__ ei, const int* __restrict__ csr_off,
    const int* __restrict__ epos, int* __restrict__ bucket_src, int E)
{
    const int e0 = (blockIdx.x * 256 + threadIdx.x) * 4;
    if (e0 + 3 < E) {
        const int4 s4 = *(const int4*)(ei + e0);
        const int4 d4 = *(const int4*)(ei + E + e0);
        const int4 p4 = *(const int4*)(epos + e0);
        bucket_src[csr_off[d4.x] + p4.x] = s4.x;
        bucket_src[csr_off[d4.y] + p4.y] = s4.y;
        bucket_src[csr_off[d4.z] + p4.z] = s4.z;
        bucket_src[csr_off[d4.w] + p4.w] = s4.w;
    } else {
        for (int j = 0; j < 4; ++j) {
            const int e = e0 + j;
            if (e < E) bucket_src[csr_off[ei[E + e]] + epos[e]] = ei[e];
        }
    }
}

// ---------------------------------------------------------------------------
// gather-reduce over h rows (128 B = exactly 1 L2 line, fully used).
// Wave: 2 edges x 32 lanes; 4 double-edge loads in flight; shfl_xor(32)
// merges slots. Writes mean as PACKED BF16 (uint = 2 feats) — halves the
// mean buffer traffic here and in final_linear; numerics identical since
// final_linear converted to bf16 for MFMA anyway.
// ---------------------------------------------------------------------------
__global__ __launch_bounds__(256) void edge_aggregate_h(
    const int* __restrict__ csr_off, const int* __restrict__ bucket_src,
    const unsigned int* __restrict__ h,   // [N][32] uints
    unsigned int* __restrict__ mean_bf,   // [N][32] uints (bf16 pairs)
    int N)
{
    const int lane = threadIdx.x & 63;
    const int u = lane & 31;      // uint index (2 feats)
    const int eo = lane >> 5;     // edge slot 0..1
    const int d0 = blockIdx.x * 32 + (threadIdx.x >> 6) * 8;

    #pragma unroll 1
    for (int i = 0; i < 8; ++i) {
        const int dst = d0 + i;
        if (dst >= N) return;
        const int base = csr_off[dst];
        const int end  = csr_off[dst + 1];
        float a0 = 0.f, a1 = 0.f;
        for (int p = base; p < end; p += 8) {
            const int e0 = p + eo;
            const int e1 = e0 + 2;
            const int e2 = e0 + 4;
            const int e3 = e0 + 6;
            const int s0 = bucket_src[(e0 < end) ? e0 : (end - 1)];
            const int s1 = bucket_src[(e1 < end) ? e1 : (end - 1)];
            const int s2 = bucket_src[(e2 < end) ? e2 : (end - 1)];
            const int s3 = bucket_src[(e3 < end) ? e3 : (end - 1)];
            const unsigned int v0 = h[(size_t)s0 * 32 + u];
            const unsigned int v1 = h[(size_t)s1 * 32 + u];
            const unsigned int v2 = h[(size_t)s2 * 32 + u];
            const unsigned int v3 = h[(size_t)s3 * 32 + u];
            const float m0 = (e0 < end) ? 1.f : 0.f;
            const float m1 = (e1 < end) ? 1.f : 0.f;
            const float m2 = (e2 < end) ? 1.f : 0.f;
            const float m3 = (e3 < end) ? 1.f : 0.f;
            a0 += m0 * bf_lo(v0) + m1 * bf_lo(v1) + m2 * bf_lo(v2) + m3 * bf_lo(v3);
            a1 += m0 * bf_hi(v0) + m1 * bf_hi(v1) + m2 * bf_hi(v2) + m3 * bf_hi(v3);
        }
        a0 += __shfl_xor(a0, 32, 64);
        a1 += __shfl_xor(a1, 32, 64);
        if (lane < 32) {
            const float d = fmaxf((float)(end - base), 1.f);
            const unsigned int lo = (unsigned short)f2bf(a0 / d);
            const unsigned int hi = (unsigned short)f2bf(a1 / d);
            mean_bf[(size_t)dst * 32 + u] = lo | (hi << 16);
        }
    }
}

// ---------------------------------------------------------------------------
// final linear via MFMA: out = relu(mean_h @ wlinT + lin_b), 0 where deg==0.
// mean is now bf16 [N][64] — direct MFMA A-fragment loads, no conversion.
// ---------------------------------------------------------------------------
__global__ __launch_bounds__(256) void final_linear(
    const short* __restrict__ mean_bf,    // [N][64] bf16
    const short* __restrict__ wlin_bf,    // [128 o][64 k]
    const float* __restrict__ lin_b,
    const int*  __restrict__ csr_off,
    float* __restrict__ out, int N)
{
    const int tid = threadIdx.x;
    const int w = tid >> 6;
    const int lane = tid & 63;
    const int c = lane & 15;
    const int quad = lane >> 4;
    const int n0 = blockIdx.x * 64;

    const int mnode = n0 + w * 16 + c;
    const int arow = (mnode < N) ? mnode : (N - 1);
    const short* aptr = mean_bf + (size_t)arow * HID + quad * 8;

    f32x4 c2[8];
    #pragma unroll
    for (int q = 0; q < 8; ++q) { c2[q][0]=0.f; c2[q][1]=0.f; c2[q][2]=0.f; c2[q][3]=0.f; }

    #pragma unroll
    for (int kt = 0; kt < 2; ++kt) {
        const bf16x8 af = *(const bf16x8*)(aptr + kt * 32);
        #pragma unroll
        for (int nt = 0; nt < 8; ++nt) {
            const bf16x8 bfr = *(const bf16x8*)(wlin_bf + (nt * 16 + c) * HID + kt * 32 + quad * 8);
            c2[nt] = __builtin_amdgcn_mfma_f32_16x16x32_bf16(af, bfr, c2[nt], 0, 0, 0);
        }
    }

    float mask[4];
    #pragma unroll
    for (int r = 0; r < 4; ++r) {
        const int nn = n0 + w * 16 + quad * 4 + r;
        const int nc = (nn < N) ? nn : (N - 1);
        mask[r] = (csr_off[nc + 1] - csr_off[nc] > 0) ? 1.f : 0.f;
    }

    #pragma unroll
    for (int nt = 0; nt < 8; ++nt) {
        const float lb = lin_b[nt * 16 + c];
        #pragma unroll
        for (int r = 0; r < 4; ++r) {
            const int nn = n0 + w * 16 + quad * 4 + r;
            if (nn < N)
                out[(size_t)nn * OUT_DIM + nt * 16 + c] =
                    mask[r] * fmaxf(c2[nt][r] + lb, 0.f);
        }
    }
}

extern "C" void kernel_launch(void* const* d_in, const int* in_sizes, int n_in,
                              void* d_out, int out_size, void* d_ws, size_t ws_size,
                              hipStream_t stream) {
    const float* node_feats = (const float*)d_in[0];
    const float* cond_feats = (const float*)d_in[1];
    const float* cond_w_v   = (const float*)d_in[2];
    const float* cond_w_g   = (const float*)d_in[3];
    const float* cond_b     = (const float*)d_in[4];
    const float* film_w     = (const float*)d_in[5];
    const float* film_b     = (const float*)d_in[6];
    const float* lin_w_v    = (const float*)d_in[7];
    const float* lin_w_g    = (const float*)d_in[8];
    const float* lin_b      = (const float*)d_in[9];
    const int* edge_index   = (const int*)d_in[10];
    const int* node2graph   = (const int*)d_in[11];

    const int N = in_sizes[0] / NODE_DIM;     // 100000
    const int B = in_sizes[1] / COND_DIM;     // 64
    const int E = in_sizes[10] / 2;           // 1600000
    const int NB = (N + 1023) / 1024;

    auto align_up = [](size_t x) { return (x + 255) & ~(size_t)255; };
    char* ws = (char*)d_ws;
    size_t off = 0;
    int* deg        = (int*)(ws + off); off += align_up((size_t)N * 4);
    int* csr_off    = (int*)(ws + off); off += align_up((size_t)(N + 1) * 4);
    int* bsums      = (int*)(ws + off); off += align_up(1024 * 4);
    int* boff       = (int*)(ws + off); off += align_up(1024 * 4);
    int* epos       = (int*)(ws + off); off += align_up((size_t)E * 4);
    int* bucket_src = (int*)(ws + off); off += align_up((size_t)E * 4);
    unsigned short* h_buf = (unsigned short*)(ws + off); off += align_up((size_t)N * HID * 2);
    unsigned int* mean_bf = (unsigned int*)(ws + off); off += align_up((size_t)N * HID * 2);
    float* gamma    = (float*)(ws + off); off += align_up((size_t)B * HID * 4);
    float* beta     = (float*)(ws + off); off += align_up((size_t)B * HID * 4);
    short* wlin_bf  = (short*)(ws + off); off += align_up((size_t)OUT_DIM * HID * 2);
    short* fw_bf    = (short*)(ws + off); off += align_up((size_t)HID * NODE_DIM * 2);

    // prep: 130 work blocks + deg-zero blocks (replaces memset launch)
    prep<<<130 + NB, 256, 0, stream>>>(cond_feats, cond_w_v, cond_w_g, cond_b,
                                       lin_w_v, lin_w_g, film_w,
                                       gamma, beta, wlin_bf, fw_bf, deg, N, B);

    // fused deg_count + node_film, pattern d,f (1:1)
    const int G_film = (N + 63) / 64;                 // 1563
    const int G_deg  = (E + 1023) / 1024;             // 1563
    const int G_max  = (G_film > G_deg) ? G_film : G_deg;
    const int G2 = 2 * G_max;
    fused_phase1<<<G2, 256, 0, stream>>>(
        node_feats, fw_bf, film_b, gamma, beta, node2graph, h_buf,
        edge_index, deg, epos, N, E, G_film, G_deg);

    scan1<<<NB, 1024, 0, stream>>>(deg, csr_off, bsums, N);
    scan2<<<1, 1024, 0, stream>>>(bsums, boff, NB);
    scan3<<<NB, 1024, 0, stream>>>(csr_off, boff, N);
    bucket_fill<<<(E / 4 + 255) / 256, 256, 0, stream>>>(edge_index, csr_off,
                                                         epos, bucket_src, E);

    edge_aggregate_h<<<(N + 31) / 32, 256, 0, stream>>>(
        csr_off, bucket_src, (const unsigned int*)h_buf, mean_bf, N);

    final_linear<<<(N + 63) / 64, 256, 0, stream>>>(
        (const short*)mean_bf, wlin_bf, lin_b, csr_off, (float*)d_out, N);
}

// Round 2
// 349.004 us; speedup vs baseline: 1.0820x; 1.0820x over previous
//
#include <hip/hip_runtime.h>
#include <hip/hip_bf16.h>

#define NODE_DIM 256
#define COND_DIM 512
#define OUT_DIM  128
#define HID      64
#define LN_EPS   1e-5f

// dst-bin partition: bins of 512 nodes -> nbin = ceil(N/512) (=196 for N=100000)
#define BIN_SHIFT 9
#define WINDOW    512
#define MAXBIN    256

typedef __attribute__((ext_vector_type(8))) short bf16x8;
typedef __attribute__((ext_vector_type(4))) float f32x4;

__device__ __forceinline__ short f2bf(float f) {
    __hip_bfloat16 h = __float2bfloat16(f);
    return *reinterpret_cast<short*>(&h);
}
__device__ __forceinline__ float bf_lo(unsigned int v) {
    union { unsigned int u; float f; } x; x.u = v << 16; return x.f;
}
__device__ __forceinline__ float bf_hi(unsigned int v) {
    union { unsigned int u; float f; } x; x.u = v & 0xffff0000u; return x.f;
}

// ---------------------------------------------------------------------------
// prep (grid 130):
//  blocks 0..127 : cond projection output o (weight-normed) -> gamma/beta
//  block 128     : weight-norm lin_w_v rows -> wlin_bf [128 o][64 k] bf16
//  block 129     : film_w -> fw_bf [64 h][256 k] bf16 ; zero bin_cnt
// ---------------------------------------------------------------------------
__global__ __launch_bounds__(256) void prep(
    const float* __restrict__ cond_feats,
    const float* __restrict__ cond_w_v,
    const float* __restrict__ cond_w_g,
    const float* __restrict__ cond_b,
    const float* __restrict__ lin_w_v,
    const float* __restrict__ lin_w_g,
    const float* __restrict__ film_w,
    float* __restrict__ gamma, float* __restrict__ beta,
    short* __restrict__ wlin_bf, short* __restrict__ fw_bf,
    int* __restrict__ bin_cnt, int nbin, int N, int B)
{
    const int t = threadIdx.x;
    const int bid = blockIdx.x;
    if (bid == 128) {
        if (t < OUT_DIM) {
            const int o = t;
            float nrm = 0.f;
            float w[HID];
            #pragma unroll
            for (int k = 0; k < HID; ++k) {
                w[k] = lin_w_v[o * HID + k];
                nrm += w[k] * w[k];
            }
            const float s = lin_w_g[o] * rsqrtf(nrm);
            #pragma unroll
            for (int k = 0; k < HID; ++k) wlin_bf[o * HID + k] = f2bf(w[k] * s);
        }
        return;
    }
    if (bid == 129) {
        if (t < nbin) bin_cnt[t] = 0;
        for (int idx = t; idx < HID * NODE_DIM; idx += 256)
            fw_bf[idx] = f2bf(film_w[idx]);
        return;
    }
    const int o = bid;
    const int lane = t & 63;
    const int wv = t >> 6;
    __shared__ float s_cp[64];
    __shared__ float s_nrm;
    float wreg[COND_DIM / 64];
    #pragma unroll
    for (int j = 0; j < COND_DIM / 64; ++j)
        wreg[j] = cond_w_v[o * COND_DIM + j * 64 + lane];
    float nr = 0.f;
    #pragma unroll
    for (int j = 0; j < COND_DIM / 64; ++j) nr += wreg[j] * wreg[j];
    #pragma unroll
    for (int off = 32; off > 0; off >>= 1) nr += __shfl_xor(nr, off, 64);
    if (t == 0) s_nrm = nr;
    for (int b = wv; b < 64; b += 4) {
        float a = 0.f;
        #pragma unroll
        for (int j = 0; j < COND_DIM / 64; ++j)
            a += wreg[j] * cond_feats[b * COND_DIM + j * 64 + lane];
        #pragma unroll
        for (int off = 32; off > 0; off >>= 1) a += __shfl_xor(a, off, 64);
        if (lane == 0) s_cp[b] = a;
    }
    __syncthreads();
    if (t < 64) {
        const float scale = cond_w_g[o] * rsqrtf(s_nrm);
        const float cp = scale * s_cp[t] + cond_b[o];
        if (o < HID) gamma[t * HID + o] = cp + 1.0f;
        else         beta[t * HID + (o - HID)] = cp;
    }
}

// ---------------------------------------------------------------------------
// fused_phase1: film path (GEMM1 + LN + FiLM + relu -> h bf16 [N][64]) fused
// with dst-bin COUNTING (LDS histogram + nbin non-returning global atomics
// per block). This replaces the 1.6M returning-atomic deg/epos scheme that
// was throughput-limited at the memory-side atomic unit.
// ---------------------------------------------------------------------------
__global__ __launch_bounds__(256) void fused_phase1(
    const float* __restrict__ nf,
    const short* __restrict__ fw_bf,      // [64 h][256 k]
    const float* __restrict__ film_b,
    const float* __restrict__ gamma, const float* __restrict__ beta,
    const int*  __restrict__ n2g,
    unsigned short* __restrict__ h_out,   // [N][64] bf16
    const int* __restrict__ ei,
    int* __restrict__ bin_cnt,
    int N, int E, int nbin)
{
    __shared__ int hist[MAXBIN];
    const int t = threadIdx.x;
    const int bid = blockIdx.x;

    // ---- bin count: 1024 edges per block --------------------------------
    hist[t] = 0;
    __syncthreads();
    const int e0 = bid * 1024 + t * 4;
    if (e0 + 3 < E) {
        const int4 d4 = *(const int4*)(ei + E + e0);
        atomicAdd(&hist[d4.x >> BIN_SHIFT], 1);
        atomicAdd(&hist[d4.y >> BIN_SHIFT], 1);
        atomicAdd(&hist[d4.z >> BIN_SHIFT], 1);
        atomicAdd(&hist[d4.w >> BIN_SHIFT], 1);
    } else {
        for (int j = 0; j < 4; ++j) {
            const int e = e0 + j;
            if (e < E) atomicAdd(&hist[ei[E + e] >> BIN_SHIFT], 1);
        }
    }
    __syncthreads();
    if (t < nbin && hist[t] > 0) atomicAdd(&bin_cnt[t], hist[t]);  // no-return

    // ---- film path ------------------------------------------------------
    const int w = t >> 6;
    const int lane = t & 63;
    const int c = lane & 15;
    const int quad = lane >> 4;
    const int n0 = bid * 64;
    if (n0 >= N) return;

    f32x4 c1[4];
    #pragma unroll
    for (int q = 0; q < 4; ++q) { c1[q][0]=0.f; c1[q][1]=0.f; c1[q][2]=0.f; c1[q][3]=0.f; }

    const int mnode = n0 + w * 16 + c;
    const int arow = (mnode < N) ? mnode : (N - 1);
    const float* aptr = nf + (size_t)arow * NODE_DIM + quad * 8;

    #pragma unroll 4
    for (int k0 = 0; k0 < NODE_DIM; k0 += 32) {
        const float4 a01 = *(const float4*)(aptr + k0);
        const float4 a23 = *(const float4*)(aptr + k0 + 4);
        bf16x8 af;
        af[0]=f2bf(a01.x); af[1]=f2bf(a01.y); af[2]=f2bf(a01.z); af[3]=f2bf(a01.w);
        af[4]=f2bf(a23.x); af[5]=f2bf(a23.y); af[6]=f2bf(a23.z); af[7]=f2bf(a23.w);
        #pragma unroll
        for (int nt = 0; nt < 4; ++nt) {
            const bf16x8 bfr = *(const bf16x8*)(fw_bf + ((nt * 16 + c) * NODE_DIM + k0 + quad * 8));
            c1[nt] = __builtin_amdgcn_mfma_f32_16x16x32_bf16(af, bfr, c1[nt], 0, 0, 0);
        }
    }

    #pragma unroll
    for (int nt = 0; nt < 4; ++nt) {
        const float b = film_b[nt * 16 + c];
        c1[nt][0] += b; c1[nt][1] += b; c1[nt][2] += b; c1[nt][3] += b;
    }

    float sum[4], sq[4];
    #pragma unroll
    for (int r = 0; r < 4; ++r) {
        sum[r] = c1[0][r] + c1[1][r] + c1[2][r] + c1[3][r];
        sq[r]  = c1[0][r]*c1[0][r] + c1[1][r]*c1[1][r]
               + c1[2][r]*c1[2][r] + c1[3][r]*c1[3][r];
    }
    #pragma unroll
    for (int off = 1; off < 16; off <<= 1) {
        #pragma unroll
        for (int r = 0; r < 4; ++r) {
            sum[r] += __shfl_xor(sum[r], off, 64);
            sq[r]  += __shfl_xor(sq[r],  off, 64);
        }
    }
    float mu[4], inv[4];
    int gid[4];
    #pragma unroll
    for (int r = 0; r < 4; ++r) {
        mu[r] = sum[r] * (1.0f / HID);
        float var = sq[r] * (1.0f / HID) - mu[r] * mu[r];
        var = fmaxf(var, 0.f);
        inv[r] = rsqrtf(var + LN_EPS);
        const int nn = n0 + w * 16 + quad * 4 + r;
        gid[r] = n2g[(nn < N) ? nn : (N - 1)];
    }

    #pragma unroll
    for (int r = 0; r < 4; ++r) {
        const int nn = n0 + w * 16 + quad * 4 + r;
        if (nn >= N) continue;
        #pragma unroll
        for (int nt = 0; nt < 4; ++nt) {
            const int col = nt * 16 + c;
            const float ga = gamma[gid[r] * HID + col];
            const float be = beta[gid[r] * HID + col];
            const float v = fmaxf(ga * ((c1[nt][r] - mu[r]) * inv[r]) + be, 0.f);
            h_out[(size_t)nn * HID + col] = (unsigned short)f2bf(v);
        }
    }
}

// ---------------------------------------------------------------------------
// bin_scan: one block. Exclusive scan of bin_cnt -> bin_off; bin_cur=bin_off;
// csr_off[N]=E.
// ---------------------------------------------------------------------------
__global__ __launch_bounds__(256) void bin_scan(
    const int* __restrict__ bin_cnt, int* __restrict__ bin_off,
    int* __restrict__ bin_cur, int* __restrict__ csr_off,
    int nbin, int N, int E)
{
    __shared__ int sA[256], sB[256];
    const int t = threadIdx.x;
    sA[t] = (t < nbin) ? bin_cnt[t] : 0;
    __syncthreads();
    int* cur = sA; int* nxt = sB;
    for (int off = 1; off < 256; off <<= 1) {
        nxt[t] = cur[t] + ((t >= off) ? cur[t - off] : 0);
        __syncthreads();
        int* tmp = cur; cur = nxt; nxt = tmp;
    }
    if (t < nbin) {
        const int excl = cur[t] - bin_cnt[t];
        bin_off[t] = excl;
        bin_cur[t] = excl;
    }
    if (t == 0) csr_off[N] = E;
}

// ---------------------------------------------------------------------------
// partition: 4096 edges/block. LDS hist -> one returning global atomic per
// (block,bin) chunk reservation (~77K total, vs 1.6M before) -> scatter
// (src,dst) int2 into part[] grouped by bin.
// ---------------------------------------------------------------------------
__global__ __launch_bounds__(256) void partition(
    const int* __restrict__ ei, int* __restrict__ bin_cur,
    int2* __restrict__ part, int E, int nbin)
{
    __shared__ int hist[MAXBIN];
    __shared__ int chunkbase[MAXBIN];
    __shared__ int cursor[MAXBIN];
    const int t = threadIdx.x;
    hist[t] = 0; cursor[t] = 0;
    __syncthreads();
    const int base = blockIdx.x * 4096;

    #pragma unroll
    for (int j = 0; j < 4; ++j) {
        const int e0 = base + j * 1024 + t * 4;
        if (e0 + 3 < E) {
            const int4 d4 = *(const int4*)(ei + E + e0);
            atomicAdd(&hist[d4.x >> BIN_SHIFT], 1);
            atomicAdd(&hist[d4.y >> BIN_SHIFT], 1);
            atomicAdd(&hist[d4.z >> BIN_SHIFT], 1);
            atomicAdd(&hist[d4.w >> BIN_SHIFT], 1);
        } else {
            for (int k = 0; k < 4; ++k) {
                const int e = e0 + k;
                if (e < E) atomicAdd(&hist[ei[E + e] >> BIN_SHIFT], 1);
            }
        }
    }
    __syncthreads();
    if (t < nbin) {
        const int cN = hist[t];
        chunkbase[t] = (cN > 0) ? atomicAdd(&bin_cur[t], cN) : 0;
    }
    __syncthreads();

    #pragma unroll
    for (int j = 0; j < 4; ++j) {
        const int e0 = base + j * 1024 + t * 4;
        if (e0 + 3 < E) {
            const int4 d4 = *(const int4*)(ei + E + e0);
            const int4 s4 = *(const int4*)(ei + e0);
            int b, r;
            b = d4.x >> BIN_SHIFT; r = atomicAdd(&cursor[b], 1);
            part[chunkbase[b] + r] = make_int2(s4.x, d4.x);
            b = d4.y >> BIN_SHIFT; r = atomicAdd(&cursor[b], 1);
            part[chunkbase[b] + r] = make_int2(s4.y, d4.y);
            b = d4.z >> BIN_SHIFT; r = atomicAdd(&cursor[b], 1);
            part[chunkbase[b] + r] = make_int2(s4.z, d4.z);
            b = d4.w >> BIN_SHIFT; r = atomicAdd(&cursor[b], 1);
            part[chunkbase[b] + r] = make_int2(s4.w, d4.w);
        } else {
            for (int k = 0; k < 4; ++k) {
                const int e = e0 + k;
                if (e < E) {
                    const int d = ei[E + e];
                    const int b = d >> BIN_SHIFT;
                    const int r = atomicAdd(&cursor[b], 1);
                    part[chunkbase[b] + r] = make_int2(ei[e], d);
                }
            }
        }
    }
}

// ---------------------------------------------------------------------------
// bin_build: one block per bin (512-node window). LDS hist over window ->
// csr_off written DIRECTLY (bin base + local exclusive scan; replaces the
// 3 global scan kernels), then counting-sort srcs into bucket_src.
// Zero global atomics.
// ---------------------------------------------------------------------------
__global__ __launch_bounds__(256) void bin_build(
    const int2* __restrict__ part, const int* __restrict__ bin_cnt,
    const int* __restrict__ bin_off, int* __restrict__ csr_off,
    int* __restrict__ bucket_src, int N)
{
    __shared__ int hist[WINDOW];
    __shared__ int sA[WINDOW], sB[WINDOW];
    __shared__ int cursor[WINDOW];
    const int b = blockIdx.x;
    const int t = threadIdx.x;
    const int base = bin_off[b];
    const int cnt  = bin_cnt[b];
    const int w0 = b << BIN_SHIFT;
    const int wsize = min(WINDOW, N - w0);

    hist[t] = 0; hist[t + 256] = 0;
    cursor[t] = 0; cursor[t + 256] = 0;
    __syncthreads();

    for (int i = t; i < cnt; i += 256)
        atomicAdd(&hist[part[base + i].y - w0], 1);
    __syncthreads();

    sA[t] = hist[t]; sA[t + 256] = hist[t + 256];
    __syncthreads();
    int* cur = sA; int* nxt = sB;
    for (int off = 1; off < WINDOW; off <<= 1) {
        nxt[t]       = cur[t]       + ((t       >= off) ? cur[t - off]       : 0);
        nxt[t + 256] = cur[t + 256] + ((t + 256 >= off) ? cur[t + 256 - off] : 0);
        __syncthreads();
        int* tmp = cur; cur = nxt; nxt = tmp;
    }
    // cur = inclusive scan; exclusive = cur[i] - hist[i]
    if (t < wsize)       csr_off[w0 + t]       = base + cur[t]       - hist[t];
    if (t + 256 < wsize) csr_off[w0 + t + 256] = base + cur[t + 256] - hist[t + 256];

    for (int i = t; i < cnt; i += 256) {
        const int2 e = part[base + i];
        const int ld = e.y - w0;
        const int r = atomicAdd(&cursor[ld], 1);
        bucket_src[base + (cur[ld] - hist[ld]) + r] = e.x;
    }
}

// ---------------------------------------------------------------------------
// gather-reduce over h rows (128 B = exactly 1 L2 line, fully used).
// ---------------------------------------------------------------------------
__global__ __launch_bounds__(256) void edge_aggregate_h(
    const int* __restrict__ csr_off, const int* __restrict__ bucket_src,
    const unsigned int* __restrict__ h,   // [N][32] uints
    unsigned int* __restrict__ mean_bf,   // [N][32] uints (bf16 pairs)
    int N)
{
    const int lane = threadIdx.x & 63;
    const int u = lane & 31;
    const int eo = lane >> 5;
    const int d0 = blockIdx.x * 32 + (threadIdx.x >> 6) * 8;

    #pragma unroll 1
    for (int i = 0; i < 8; ++i) {
        const int dst = d0 + i;
        if (dst >= N) return;
        const int base = csr_off[dst];
        const int end  = csr_off[dst + 1];
        float a0 = 0.f, a1 = 0.f;
        for (int p = base; p < end; p += 8) {
            const int e0 = p + eo;
            const int e1 = e0 + 2;
            const int e2 = e0 + 4;
            const int e3 = e0 + 6;
            const int s0 = bucket_src[(e0 < end) ? e0 : (end - 1)];
            const int s1 = bucket_src[(e1 < end) ? e1 : (end - 1)];
            const int s2 = bucket_src[(e2 < end) ? e2 : (end - 1)];
            const int s3 = bucket_src[(e3 < end) ? e3 : (end - 1)];
            const unsigned int v0 = h[(size_t)s0 * 32 + u];
            const unsigned int v1 = h[(size_t)s1 * 32 + u];
            const unsigned int v2 = h[(size_t)s2 * 32 + u];
            const unsigned int v3 = h[(size_t)s3 * 32 + u];
            const float m0 = (e0 < end) ? 1.f : 0.f;
            const float m1 = (e1 < end) ? 1.f : 0.f;
            const float m2 = (e2 < end) ? 1.f : 0.f;
            const float m3 = (e3 < end) ? 1.f : 0.f;
            a0 += m0 * bf_lo(v0) + m1 * bf_lo(v1) + m2 * bf_lo(v2) + m3 * bf_lo(v3);
            a1 += m0 * bf_hi(v0) + m1 * bf_hi(v1) + m2 * bf_hi(v2) + m3 * bf_hi(v3);
        }
        a0 += __shfl_xor(a0, 32, 64);
        a1 += __shfl_xor(a1, 32, 64);
        if (lane < 32) {
            const float d = fmaxf((float)(end - base), 1.f);
            const unsigned int lo = (unsigned short)f2bf(a0 / d);
            const unsigned int hi = (unsigned short)f2bf(a1 / d);
            mean_bf[(size_t)dst * 32 + u] = lo | (hi << 16);
        }
    }
}

// ---------------------------------------------------------------------------
// final linear via MFMA: out = relu(mean_h @ wlinT + lin_b), 0 where deg==0.
// ---------------------------------------------------------------------------
__global__ __launch_bounds__(256) void final_linear(
    const short* __restrict__ mean_bf,    // [N][64] bf16
    const short* __restrict__ wlin_bf,    // [128 o][64 k]
    const float* __restrict__ lin_b,
    const int*  __restrict__ csr_off,
    float* __restrict__ out, int N)
{
    const int tid = threadIdx.x;
    const int w = tid >> 6;
    const int lane = tid & 63;
    const int c = lane & 15;
    const int quad = lane >> 4;
    const int n0 = blockIdx.x * 64;

    const int mnode = n0 + w * 16 + c;
    const int arow = (mnode < N) ? mnode : (N - 1);
    const short* aptr = mean_bf + (size_t)arow * HID + quad * 8;

    f32x4 c2[8];
    #pragma unroll
    for (int q = 0; q < 8; ++q) { c2[q][0]=0.f; c2[q][1]=0.f; c2[q][2]=0.f; c2[q][3]=0.f; }

    #pragma unroll
    for (int kt = 0; kt < 2; ++kt) {
        const bf16x8 af = *(const bf16x8*)(aptr + kt * 32);
        #pragma unroll
        for (int nt = 0; nt < 8; ++nt) {
            const bf16x8 bfr = *(const bf16x8*)(wlin_bf + (nt * 16 + c) * HID + kt * 32 + quad * 8);
            c2[nt] = __builtin_amdgcn_mfma_f32_16x16x32_bf16(af, bfr, c2[nt], 0, 0, 0);
        }
    }

    float mask[4];
    #pragma unroll
    for (int r = 0; r < 4; ++r) {
        const int nn = n0 + w * 16 + quad * 4 + r;
        const int nc = (nn < N) ? nn : (N - 1);
        mask[r] = (csr_off[nc + 1] - csr_off[nc] > 0) ? 1.f : 0.f;
    }

    #pragma unroll
    for (int nt = 0; nt < 8; ++nt) {
        const float lb = lin_b[nt * 16 + c];
        #pragma unroll
        for (int r = 0; r < 4; ++r) {
            const int nn = n0 + w * 16 + quad * 4 + r;
            if (nn < N)
                out[(size_t)nn * OUT_DIM + nt * 16 + c] =
                    mask[r] * fmaxf(c2[nt][r] + lb, 0.f);
        }
    }
}

extern "C" void kernel_launch(void* const* d_in, const int* in_sizes, int n_in,
                              void* d_out, int out_size, void* d_ws, size_t ws_size,
                              hipStream_t stream) {
    const float* node_feats = (const float*)d_in[0];
    const float* cond_feats = (const float*)d_in[1];
    const float* cond_w_v   = (const float*)d_in[2];
    const float* cond_w_g   = (const float*)d_in[3];
    const float* cond_b     = (const float*)d_in[4];
    const float* film_w     = (const float*)d_in[5];
    const float* film_b     = (const float*)d_in[6];
    const float* lin_w_v    = (const float*)d_in[7];
    const float* lin_w_g    = (const float*)d_in[8];
    const float* lin_b      = (const float*)d_in[9];
    const int* edge_index   = (const int*)d_in[10];
    const int* node2graph   = (const int*)d_in[11];

    const int N = in_sizes[0] / NODE_DIM;     // 100000
    const int B = in_sizes[1] / COND_DIM;     // 64
    const int E = in_sizes[10] / 2;           // 1600000
    const int nbin = (N + WINDOW - 1) >> BIN_SHIFT;   // 196

    auto align_up = [](size_t x) { return (x + 255) & ~(size_t)255; };
    char* ws = (char*)d_ws;
    size_t off = 0;
    int* csr_off    = (int*)(ws + off); off += align_up((size_t)(N + 1) * 4);
    int* bin_cnt    = (int*)(ws + off); off += align_up(MAXBIN * 4);
    int* bin_off    = (int*)(ws + off); off += align_up(MAXBIN * 4);
    int* bin_cur    = (int*)(ws + off); off += align_up(MAXBIN * 4);
    int2* part      = (int2*)(ws + off); off += align_up((size_t)E * 8);
    int* bucket_src = (int*)(ws + off); off += align_up((size_t)E * 4);
    unsigned short* h_buf = (unsigned short*)(ws + off); off += align_up((size_t)N * HID * 2);
    unsigned int* mean_bf = (unsigned int*)(ws + off); off += align_up((size_t)N * HID * 2);
    float* gamma    = (float*)(ws + off); off += align_up((size_t)B * HID * 4);
    float* beta     = (float*)(ws + off); off += align_up((size_t)B * HID * 4);
    short* wlin_bf  = (short*)(ws + off); off += align_up((size_t)OUT_DIM * HID * 2);
    short* fw_bf    = (short*)(ws + off); off += align_up((size_t)HID * NODE_DIM * 2);

    prep<<<130, 256, 0, stream>>>(cond_feats, cond_w_v, cond_w_g, cond_b,
                                  lin_w_v, lin_w_g, film_w,
                                  gamma, beta, wlin_bf, fw_bf, bin_cnt, nbin, N, B);

    const int G_film = (N + 63) / 64;
    const int G_edge = (E + 1023) / 1024;
    const int G1 = (G_film > G_edge) ? G_film : G_edge;
    fused_phase1<<<G1, 256, 0, stream>>>(
        node_feats, fw_bf, film_b, gamma, beta, node2graph, h_buf,
        edge_index, bin_cnt, N, E, nbin);

    bin_scan<<<1, 256, 0, stream>>>(bin_cnt, bin_off, bin_cur, csr_off, nbin, N, E);

    partition<<<(E + 4095) / 4096, 256, 0, stream>>>(edge_index, bin_cur, part, E, nbin);

    bin_build<<<nbin, 256, 0, stream>>>(part, bin_cnt, bin_off, csr_off,
                                        bucket_src, N);

    edge_aggregate_h<<<(N + 31) / 32, 256, 0, stream>>>(
        csr_off, bucket_src, (const unsigned int*)h_buf, mean_bf, N);

    final_linear<<<(N + 63) / 64, 256, 0, stream>>>(
        (const short*)mean_bf, wlin_bf, lin_b, csr_off, (float*)d_out, N);
}